// Round 2
// baseline (1367.501 us; speedup 1.0000x reference)
//
#include <hip/hip_runtime.h>
#include <hip/hip_bf16.h>
#include <math.h>

// Problem constants
constexpr int kB = 256, kS = 20, kE = 128, kH = 256;
constexpr int kTotalW = 2768;           // 432+16 + 2304+16
constexpr float kSlope = 1.0f / 5.5f;

typedef __bf16 bf16x8 __attribute__((ext_vector_type(8)));
typedef float  floatx4 __attribute__((ext_vector_type(4)));

// ---------------------------------------------------------------------------
// zero-fill (ws is poisoned 0xAA every call)
__global__ void zero_f32(float* __restrict__ p, int n) {
    for (int i = blockIdx.x * blockDim.x + threadIdx.x; i < n; i += gridDim.x * blockDim.x)
        p[i] = 0.f;
}

// rowmajor fp32 -> bf16 (RNE)
__global__ void cvt_bf16(const float* __restrict__ in, __bf16* __restrict__ out, int n) {
    for (int i = blockIdx.x * blockDim.x + threadIdx.x; i < n; i += gridDim.x * blockDim.x)
        out[i] = (__bf16)in[i];
}

// fp32 -> bf16 hi + bf16 lo residual (compensated split for LSTM recurrence)
__global__ void wsplit_bf16(const float* __restrict__ w, __bf16* __restrict__ whi,
                            __bf16* __restrict__ wlo, int n) {
    for (int i = blockIdx.x * blockDim.x + threadIdx.x; i < n; i += gridDim.x * blockDim.x) {
        float v = w[i];
        __bf16 hi = (__bf16)v;
        whi[i] = hi;
        wlo[i] = (__bf16)(v - (float)hi);
    }
}

// W (K x N fp32, row-major) -> Wt (N x K bf16, row-major). grid (K/32, ceil(N/32)), block 256.
__global__ __launch_bounds__(256) void transpose_cvt(
    const float* __restrict__ W, __bf16* __restrict__ Wt, int K, int N) {
    __shared__ float t[32][33];
    const int k0 = blockIdx.x * 32, n0 = blockIdx.y * 32;
    const int tx = threadIdx.x & 31, ty = threadIdx.x >> 5;   // 32 x 8
#pragma unroll
    for (int j = 0; j < 32; j += 8) {
        int n = n0 + tx, k = k0 + ty + j;
        t[ty + j][tx] = (n < N) ? W[(size_t)k * N + n] : 0.f;
    }
    __syncthreads();
#pragma unroll
    for (int j = 0; j < 32; j += 8) {
        int n = n0 + ty + j, k = k0 + tx;
        if (n < N) Wt[(size_t)n * K + k] = (__bf16)t[tx][ty + j];
    }
}

// ---------------------------------------------------------------------------
// async 16B global -> LDS (direct-to-LDS DMA; dest = wave-uniform base + lane*16)
__device__ __forceinline__ void gload16(const __bf16* g, __bf16* l) {
    __builtin_amdgcn_global_load_lds(
        (const __attribute__((address_space(1))) void*)g,
        (__attribute__((address_space(3))) void*)l, 16, 0, 0);
}

// ---------------------------------------------------------------------------
// bf16 MFMA split-K GEMM, m97 structure: 128x128 tile, BK=64, global_load_lds
// width-16 staging, single-buffer 2-barrier K-loop.
// Cacc(M,N fp32, pre-zeroed) += A(MxK bf16) @ Bt(NxK bf16)^T.
// 4 waves in a 2x2 grid, each wave owns a 64x64 sub-tile (acc[4][4] of 16x16).
// Fragment layouts (verified): A/B [outer=lane&15][k=(lane>>4)*8+j],
// C/D col=lane&15, row=(lane>>4)*4+reg.
// LDS linear [128][64] bf16 (no pad: global_load_lds needs contiguous dest).
// N not multiple of 128 handled by clamping B gather row (dup reads, garbage
// acc columns never stored). M, K must be multiples of 128/64 (true here).
__global__ __launch_bounds__(256) void mfma128(
    const __bf16* __restrict__ A, const __bf16* __restrict__ Bt,
    float* __restrict__ Cacc, int M, int N, int K, int Kchunk) {
    __shared__ __bf16 As[128 * 64];
    __shared__ __bf16 Bs[128 * 64];
    const int m0 = blockIdx.x * 128, n0 = blockIdx.y * 128;
    const int kbeg = blockIdx.z * Kchunk, kend = kbeg + Kchunk;
    const int tid = threadIdx.x, lane = tid & 63, wave = tid >> 6;
    const int wr = (wave >> 1) * 64, wc = (wave & 1) * 64;
    const int srow = lane >> 3, scol = (lane & 7) * 8;   // staging: lane -> (row, 16B seg)
    const int lrow = lane & 15, lk = (lane >> 4) * 8;    // frag read offsets
    floatx4 acc[4][4] = {};

    for (int k0 = kbeg; k0 < kend; k0 += 64) {
        // stage A/B 128x64 tiles: 8 chunks/wave, 1 KiB (8 rows) each, direct to LDS
#pragma unroll
        for (int c = 0; c < 4; ++c) {
            const int ch = wave * 4 + c;           // chunk 0..15 -> rows ch*8..ch*8+7
            const int rr = ch * 8 + srow;
            gload16(A + (size_t)(m0 + rr) * K + k0 + scol, &As[ch * 512]);
            int nr = n0 + rr; if (nr > N - 1) nr = N - 1;
            gload16(Bt + (size_t)nr * K + k0 + scol, &Bs[ch * 512]);
        }
        __syncthreads();                            // drains vmcnt -> tiles ready
#pragma unroll
        for (int ks = 0; ks < 2; ++ks) {
            bf16x8 af[4], bfv[4];
#pragma unroll
            for (int m = 0; m < 4; ++m)
                af[m] = *(const bf16x8*)&As[(wr + m * 16 + lrow) * 64 + ks * 32 + lk];
#pragma unroll
            for (int n = 0; n < 4; ++n)
                bfv[n] = *(const bf16x8*)&Bs[(wc + n * 16 + lrow) * 64 + ks * 32 + lk];
#pragma unroll
            for (int m = 0; m < 4; ++m)
#pragma unroll
                for (int n = 0; n < 4; ++n)
                    acc[m][n] = __builtin_amdgcn_mfma_f32_16x16x32_bf16(
                        af[m], bfv[n], acc[m][n], 0, 0, 0);
        }
        __syncthreads();
    }
    const int col = lane & 15, rq = (lane >> 4) * 4;
#pragma unroll
    for (int m = 0; m < 4; ++m)
#pragma unroll
        for (int n = 0; n < 4; ++n)
#pragma unroll
            for (int r = 0; r < 4; ++r) {
                int gm = m0 + wr + m * 16 + rq + r, gn = n0 + wc + n * 16 + col;
                if (gn < N) atomicAdd(&Cacc[(size_t)gm * N + gn], acc[m][n][r]);
            }
}

// epilogues: bias + leaky-relu -> bf16 (feeds next MFMA GEMM) / bias only -> fp32
__global__ void ep_lrelu_bf16(const float* __restrict__ acc, const float* __restrict__ bias,
                              __bf16* __restrict__ out, int M, int N) {
    int i = blockIdx.x * blockDim.x + threadIdx.x;
    if (i < M * N) {
        float v = acc[i] + bias[i % N];
        out[i] = (__bf16)(v > 0.f ? v : v * kSlope);
    }
}
__global__ void ep_bias_f32(const float* __restrict__ acc, const float* __restrict__ bias,
                            float* __restrict__ out, int M, int N) {
    int i = blockIdx.x * blockDim.x + threadIdx.x;
    if (i < M * N) out[i] = acc[i] + bias[i % N];
}

// ---------------------------------------------------------------------------
// xih via MFMA: xih[(s*B+b)*4H + n] = embb[q[b,s]] . w_ihb[n,:] + b_ih[n] + b_hh[n]
// A rows gathered via qs; w_ihb (4H x E) row-major == Bt layout. grid (80,16).
__global__ __launch_bounds__(256) void xih_mfma(
    const int* __restrict__ questions, const __bf16* __restrict__ embb,
    const __bf16* __restrict__ w_ihb, const float* __restrict__ b_ih,
    const float* __restrict__ b_hh, float* __restrict__ xih) {
    __shared__ __bf16 As[64][72];
    __shared__ __bf16 Bs[64][72];
    __shared__ int qs[64];
    const int m0 = blockIdx.x * 64, n0 = blockIdx.y * 64;
    const int tid = threadIdx.x, lane = tid & 63, wave = tid >> 6;
    if (tid < 64) {
        int m = m0 + tid;
        qs[tid] = questions[(m % kB) * kS + (m / kB)];
    }
    __syncthreads();
    floatx4 acc[4] = {};
    for (int k0 = 0; k0 < kE; k0 += 64) {
        for (int i = tid; i < 512; i += 256) {
            int r = i >> 3, seg = i & 7;
            *(uint4*)(&As[r][seg * 8]) =
                *(const uint4*)(embb + (size_t)qs[r] * kE + k0 + seg * 8);
        }
        for (int i = tid; i < 512; i += 256) {
            int r = i >> 3, seg = i & 7;
            *(uint4*)(&Bs[r][seg * 8]) =
                *(const uint4*)(w_ihb + (size_t)(n0 + r) * kE + k0 + seg * 8);
        }
        __syncthreads();
#pragma unroll
        for (int ks = 0; ks < 2; ++ks) {
            bf16x8 af = *(const bf16x8*)(&As[wave * 16 + (lane & 15)][ks * 32 + (lane >> 4) * 8]);
#pragma unroll
            for (int nb = 0; nb < 4; ++nb) {
                bf16x8 bfr = *(const bf16x8*)(&Bs[nb * 16 + (lane & 15)][ks * 32 + (lane >> 4) * 8]);
                acc[nb] = __builtin_amdgcn_mfma_f32_16x16x32_bf16(af, bfr, acc[nb], 0, 0, 0);
            }
        }
        __syncthreads();
    }
    const int col = lane & 15, rq = (lane >> 4) * 4;
#pragma unroll
    for (int nb = 0; nb < 4; ++nb)
#pragma unroll
        for (int r = 0; r < 4; ++r) {
            int m = m0 + wave * 16 + rq + r, n = n0 + nb * 16 + col;
            xih[(size_t)m * 1024 + n] = acc[nb][r] + b_ih[n] + b_hh[n];
        }
}

// ---------------------------------------------------------------------------
// Persistent LSTM: ALL 20 steps in one kernel. Batch-parallel (h[b],c[b] depend
// only on batch row b) -> no grid sync. Grid 16 blocks x 256 thr (4 waves).
// Block bi owns batch rows b0=bi*16..+15; wave w owns j-slice [w*64,(w+1)*64)
// of h for ALL 4 gates (rows g*256 + w*64 + jt*16 + .. of w_hh).
// gates = xih[t] + h @ w_hh^T via MFMA with compensated bf16 split:
//   h@w ~= hhi@whi + hlo@whi + hhi@wlo   (lo*lo dropped, rel err ~2^-18)
// B-fragments read DIRECTLY from global (w_hh hi/lo = 1MB total, L2-resident;
// one frag instr = 16 rows x 64B contiguous segments -> coalesced).
// h round-trips through LDS (cross-wave A-operand); c stays in registers.
__global__ __launch_bounds__(256, 1) void lstm_all(
    const float* __restrict__ xih,    // (20,256,1024), row m = t*256+b
    const __bf16* __restrict__ whi,   // (1024,256) bf16 hi
    const __bf16* __restrict__ wlo,   // (1024,256) bf16 lo residual
    __bf16* __restrict__ h0b) {       // (256,256) final h, bf16
    __shared__ float hs[16][268];     // row stride 268: 4-rows apart = 16 banks off
    const int tid = threadIdx.x, lane = tid & 63, wv = tid >> 6;
    const int b0 = blockIdx.x * 16;
    const int col = lane & 15, rq = (lane >> 4) * 4;   // C/D: row=rq+r, col
    const int arow = lane & 15, ak = (lane >> 4) * 8;  // A/B frag: outer row, k ofs
    float c_reg[4][4] = {};                            // [jt][r]

    for (int t = 0; t < kS; ++t) {
        // init acc from xih (additive gate bias term)
        floatx4 acc[4][4];                             // [g][jt], elems = r
        const float* xb = xih + ((size_t)t * kB + b0) * 1024;
#pragma unroll
        for (int g = 0; g < 4; ++g)
#pragma unroll
            for (int jt = 0; jt < 4; ++jt) {
                int n = g * 256 + wv * 64 + jt * 16 + col;
#pragma unroll
                for (int r = 0; r < 4; ++r)
                    acc[g][jt][r] = xb[(size_t)(rq + r) * 1024 + n];
            }
        if (t > 0) {
            // A-fragments from hs, split hi/lo
            bf16x8 ahi[8], alo[8];
#pragma unroll
            for (int ks = 0; ks < 8; ++ks) {
                union { bf16x8 v; __bf16 e[8]; } uh, ul;
#pragma unroll
                for (int j = 0; j < 8; ++j) {
                    float v = hs[arow][ks * 32 + ak + j];
                    __bf16 hi = (__bf16)v;
                    uh.e[j] = hi;
                    ul.e[j] = (__bf16)(v - (float)hi);
                }
                ahi[ks] = uh.v; alo[ks] = ul.v;
            }
            __syncthreads();   // all waves done reading hs (uniform branch)
            // K-loop: barrier-free, B-frags straight from global (L2-hot)
#pragma unroll
            for (int ks = 0; ks < 8; ++ks) {
                bf16x8 bh[16], bl[16];
#pragma unroll
                for (int nt = 0; nt < 16; ++nt) {
                    int g = nt >> 2, jt = nt & 3;
                    size_t ofs = (size_t)(g * 256 + wv * 64 + jt * 16 + arow) * 256
                               + ks * 32 + ak;
                    bh[nt] = *(const bf16x8*)(whi + ofs);
                    bl[nt] = *(const bf16x8*)(wlo + ofs);
                }
#pragma unroll
                for (int nt = 0; nt < 16; ++nt) {
                    int g = nt >> 2, jt = nt & 3;
                    acc[g][jt] = __builtin_amdgcn_mfma_f32_16x16x32_bf16(
                        ahi[ks], bh[nt], acc[g][jt], 0, 0, 0);
                    acc[g][jt] = __builtin_amdgcn_mfma_f32_16x16x32_bf16(
                        alo[ks], bh[nt], acc[g][jt], 0, 0, 0);
                    acc[g][jt] = __builtin_amdgcn_mfma_f32_16x16x32_bf16(
                        ahi[ks], bl[nt], acc[g][jt], 0, 0, 0);
                }
            }
        }
        // epilogue: gate nonlinearities, c/h update, h -> LDS (and final store)
#pragma unroll
        for (int jt = 0; jt < 4; ++jt)
#pragma unroll
            for (int r = 0; r < 4; ++r) {
                float gi = acc[0][jt][r], gf = acc[1][jt][r];
                float gg = acc[2][jt][r], go = acc[3][jt][r];
                float i_ = 1.f / (1.f + expf(-gi));
                float f_ = 1.f / (1.f + expf(-gf));
                float g_ = tanhf(gg);
                float o_ = 1.f / (1.f + expf(-go));
                float c = f_ * c_reg[jt][r] + i_ * g_;
                c_reg[jt][r] = c;
                float h = o_ * tanhf(c);
                int j = wv * 64 + jt * 16 + col;
                hs[rq + r][j] = h;
                if (t == kS - 1)
                    h0b[(size_t)(b0 + rq + r) * kH + j] = (__bf16)h;
            }
        __syncthreads();   // h visible to all waves before next step's reads
    }
}

__global__ void bias_relu(const float* __restrict__ acc, const float* __restrict__ bias,
                          float* __restrict__ out, int M, int N) {
    int i = blockIdx.x * blockDim.x + threadIdx.x;
    if (i < M * N) {
        int n = i % N;
        out[i] = fmaxf(acc[i] + bias[n], 0.f);
    }
}

// ---------------------------------------------------------------------------
// MFMA tap-pair fused conv1(3->16) + conv2(16->16), 3x3, pad 1, no act between.
// One block = one sample x one 8-row output slab. Both convs use the SAME
// decomposition: K=32 MFMA covers tap-pair p (k<16 -> tap 2p, k>=16 -> tap 2p+1);
// A[o][k] holds the weights (zeros for c>=Cin or tap 9), B read from channel-
// contiguous LDS [row][col][ch16] (32B col stride, 16B-aligned b128 reads).
// Zero padding (image border AND conv2's padding of conv1 output) comes from
// the LDS memset: invalid rows are simply skipped.
constexpr int ICH = 16;   // img_s channel stride (bf16)
constexpr int MCH = 16;   // mid_s channel stride (bf16)

__global__ __launch_bounds__(256) void conv_fused_mfma(
    const float* __restrict__ img,     // (B,3,64,64)
    const float* __restrict__ all_w,   // (B,2768)
    __bf16* __restrict__ out) {        // (B,16,64,64) bf16
    const int b = blockIdx.y;
    const int y0 = blockIdx.x * 8;
    __shared__ __align__(16) __bf16 w1a[5 * 16 * 32];         // [pair][o][k]
    __shared__ __align__(16) __bf16 w2a[5 * 16 * 32];         // [pair][o][k]
    __shared__ float bias_s[32];                              // conv1 | conv2 bias
    __shared__ __align__(16) __bf16 img_s[12 * 66 * ICH];     // rows gy=y0-2..y0+9
    __shared__ __align__(16) __bf16 mid_s[10 * 66 * MCH];     // rows gy=y0-1..y0+8

    const int tid = threadIdx.x, lane = tid & 63, wave = tid >> 6;
    const float* wb = all_w + (size_t)b * kTotalW;

    // ---- phase A0: memset both LDS tiles (halo zeros + pad channels), weights ----
    for (int i = tid; i < 12 * 66 * ICH / 8; i += 256)
        ((uint4*)img_s)[i] = make_uint4(0u, 0u, 0u, 0u);
    for (int i = tid; i < 10 * 66 * MCH / 8; i += 256)
        ((uint4*)mid_s)[i] = make_uint4(0u, 0u, 0u, 0u);
    for (int i = tid; i < 2560; i += 256) {      // w1a: k=half*16+c, t=2p+half
        int p = i >> 9, rem = i & 511, o = rem >> 5, k = rem & 31;
        int half = k >> 4, c = k & 15, t = 2 * p + half;
        w1a[i] = (__bf16)((c < 3 && t < 9) ? wb[o * 27 + c * 9 + t] : 0.f);
    }
    for (int i = tid; i < 2560; i += 256) {      // w2a
        int p = i >> 9, rem = i & 511, o = rem >> 5, k = rem & 31;
        int half = k >> 4, c = k & 15, t = 2 * p + half;
        w2a[i] = (__bf16)((t < 9) ? wb[448 + (o * 16 + c) * 9 + t] : 0.f);
    }
    if (tid < 16) bias_s[tid] = wb[432 + tid];
    else if (tid < 32) bias_s[tid] = wb[2752 + (tid - 16)];
    __syncthreads();

    // ---- phase A1: fill real image pixels (coalesced global reads) ----
    for (int i = tid; i < 3 * 12 * 64; i += 256) {
        int c = i / 768, rem = i - c * 768, r = rem >> 6, x = rem & 63;
        int gy = y0 - 2 + r;
        if (gy >= 0 && gy < 64)
            img_s[(r * 66 + (x + 1)) * ICH + c] =
                (__bf16)img[(((size_t)b * 3 + c) << 12) + (gy << 6) + x];
    }
    __syncthreads();

    // per-lane fragment constants (shared by both convs)
    const int n = lane & 15, half = lane >> 5;
    const int c0 = ((lane >> 4) & 1) * 8, o0 = (lane >> 4) * 4;
    int dy_[5], dx_[5];
#pragma unroll
    for (int p = 0; p < 5; ++p) {
        int t = 2 * p + half;
        dy_[p] = (t < 9) ? t / 3 : 0;
        dx_[p] = (t < 9) ? t % 3 : 0;
    }
    bf16x8 a1[5], a2[5];
#pragma unroll
    for (int p = 0; p < 5; ++p) {
        a1[p] = *(const bf16x8*)&w1a[p * 512 + n * 32 + (lane >> 4) * 8];
        a2[p] = *(const bf16x8*)&w2a[p * 512 + n * 32 + (lane >> 4) * 8];
    }

    // ---- phase B: conv1, 40 tiles (10 mid-rows x 4 x-tiles), 10 per wave ----
#pragma unroll
    for (int ti = 0; ti < 10; ++ti) {
        int tile = wave * 10 + ti;
        int rr = tile >> 2, xt = (tile & 3) * 16;
        int gy = y0 - 1 + rr;                    // mid row's global y
        if (gy >= 0 && gy < 64) {                // else: stays zero (conv2's padding)
            floatx4 acc = {};
#pragma unroll
            for (int p = 0; p < 5; ++p) {
                bf16x8 bfr = *(const bf16x8*)
                    &img_s[((rr + dy_[p]) * 66 + (xt + n + dx_[p])) * ICH + c0];
                acc = __builtin_amdgcn_mfma_f32_16x16x32_bf16(a1[p], bfr, acc, 0, 0, 0);
            }
            union { short4 s4; __bf16 h[4]; } u;
#pragma unroll
            for (int q = 0; q < 4; ++q) u.h[q] = (__bf16)(acc[q] + bias_s[o0 + q]);
            *(short4*)&mid_s[(rr * 66 + (xt + n + 1)) * MCH + o0] = u.s4;
        }
    }
    __syncthreads();

    // ---- phase C: conv2, 32 tiles (8 rows x 4 x-tiles), 8 per wave ----
#pragma unroll
    for (int ti = 0; ti < 8; ++ti) {
        int tile = wave * 8 + ti;
        int rr = tile >> 2, xt = (tile & 3) * 16;
        floatx4 acc = {};
#pragma unroll
        for (int p = 0; p < 5; ++p) {
            bf16x8 bfr = *(const bf16x8*)
                &mid_s[((rr + dy_[p]) * 66 + (xt + n + dx_[p])) * MCH + c0];
            acc = __builtin_amdgcn_mfma_f32_16x16x32_bf16(a2[p], bfr, acc, 0, 0, 0);
        }
        int gy = y0 + rr, gx = xt + n;
#pragma unroll
        for (int q = 0; q < 4; ++q)
            out[(((size_t)b * 16 + o0 + q) * 64 + gy) * 64 + gx] =
                (__bf16)(acc[q] + bias_s[16 + o0 + q]);
    }
}

// ---------------------------------------------------------------------------
// Fused lin2+lin3: out(256,2). grid B, block 64.
__global__ __launch_bounds__(64) void lin23(
    const float* __restrict__ l1out,
    const float* __restrict__ lw2, const float* __restrict__ lb2,
    const float* __restrict__ lw3, const float* __restrict__ lb3,
    float* __restrict__ out) {
    const int b = blockIdx.x, j = threadIdx.x;
    __shared__ float row[512];
    __shared__ float s[64];
    for (int i = j; i < 512; i += 64) row[i] = l1out[(size_t)b * 512 + i];
    __syncthreads();
    float acc = lb2[j];
    for (int k = 0; k < 512; ++k) acc += row[k] * lw2[(size_t)k * 64 + j];
    s[j] = fmaxf(acc, 0.f);
    __syncthreads();
    if (j < 2) {
        float o = lb3[j];
        for (int k = 0; k < 64; ++k) o += s[k] * lw3[(size_t)k * 2 + j];
        out[(size_t)b * 2 + j] = o;
    }
}

// ---------------------------------------------------------------------------
extern "C" void kernel_launch(void* const* d_in, const int* in_sizes, int n_in,
                              void* d_out, int out_size, void* d_ws, size_t ws_size,
                              hipStream_t stream) {
    const int* questions = (const int*)d_in[0];
    const float* images  = (const float*)d_in[1];
    const float* emb     = (const float*)d_in[2];
    const float* w_ih    = (const float*)d_in[3];
    const float* w_hh    = (const float*)d_in[4];
    const float* b_ih    = (const float*)d_in[5];
    const float* b_hh    = (const float*)d_in[6];
    const float* hw1     = (const float*)d_in[7];
    const float* hb1     = (const float*)d_in[8];
    const float* hw2     = (const float*)d_in[9];
    const float* hb2     = (const float*)d_in[10];
    const float* hw3     = (const float*)d_in[11];
    const float* hb3     = (const float*)d_in[12];
    const float* lw1     = (const float*)d_in[13];
    const float* lb1     = (const float*)d_in[14];
    const float* lw2     = (const float*)d_in[15];
    const float* lb2     = (const float*)d_in[16];
    const float* lw3     = (const float*)d_in[17];
    const float* lb3     = (const float*)d_in[18];
    float* out = (float*)d_out;

    char* ws = (char*)d_ws;
    size_t off = 0;
    auto alloc = [&](size_t nbytes) -> void* {
        void* p = (void*)(ws + off);
        off += (nbytes + 255) & ~(size_t)255;
        return p;
    };
    // big (64MB) timeline (single stream, strictly ordered):
    //   [0..20MB)  xih fp32            (dead after LSTM)
    //   [24..47MB) w3t bf16            (dead after hw3 MFMA GEMM)
    //   [0..32MB)  conv out bf16       (written by conv_fused_mfma, after both above dead)
    float*  big   = (float*)alloc(64ull << 20);
    __bf16* lw1t  = (__bf16*)alloc((size_t)512 * 65536 * 2);   // lw1^T bf16
    __bf16* w1t   = (__bf16*)alloc((size_t)1024 * 256 * 2);    // hw1^T bf16
    __bf16* w2t   = (__bf16*)alloc((size_t)4096 * 1024 * 2);   // hw2^T bf16
    __bf16* embb  = (__bf16*)alloc((size_t)10000 * kE * 2);    // emb bf16
    __bf16* w_ihb = (__bf16*)alloc((size_t)1024 * kE * 2);     // w_ih bf16 (already (N,K))
    __bf16* whib  = (__bf16*)alloc((size_t)1024 * kH * 2);     // w_hh bf16 hi
    __bf16* wlob  = (__bf16*)alloc((size_t)1024 * kH * 2);     // w_hh bf16 lo residual
    __bf16* h0b   = (__bf16*)alloc((size_t)kB * kH * 2);
    __bf16* h1b   = (__bf16*)alloc((size_t)kB * 1024 * 2);
    __bf16* h2b   = (__bf16*)alloc((size_t)kB * 4096 * 2);
    // contiguous fp32 accumulators (zeroed in one kernel): hw1 | hw2 | hw3 | lin1
    float*  accz  = (float*)alloc((size_t)kB * (1024 + 4096 + 2768 + 512) * sizeof(float));
    float*  accA  = accz;
    float*  accB  = accA + (size_t)kB * 1024;
    float*  accC  = accB + (size_t)kB * 4096;
    float*  acc1  = accC + (size_t)kB * 2768;
    float*  allw  = (float*)alloc((size_t)kB * kTotalW * sizeof(float));
    float*  l1out = (float*)alloc((size_t)kB * 512 * sizeof(float));

    float*  xih    = big;
    __bf16* c2out  = (__bf16*)big;
    __bf16* w3t    = (__bf16*)((char*)big + (24ull << 20));    // 2768 x 4096 bf16
    const int nACC = kB * (1024 + 4096 + 2768 + 512);
    zero_f32<<<512, 256, 0, stream>>>(accz, nACC);

    // weight converts/transposes (regions disjoint from their concurrent readers/writers)
    cvt_bf16<<<1280, 256, 0, stream>>>(emb, embb, 10000 * kE);
    cvt_bf16<<<128, 256, 0, stream>>>(w_ih, w_ihb, 1024 * kE);
    wsplit_bf16<<<256, 256, 0, stream>>>(w_hh, whib, wlob, 1024 * kH);
    transpose_cvt<<<dim3(8, 32),   256, 0, stream>>>(hw1, w1t, 256, 1024);
    transpose_cvt<<<dim3(32, 128), 256, 0, stream>>>(hw2, w2t, 1024, 4096);
    transpose_cvt<<<dim3(128, 87), 256, 0, stream>>>(hw3, w3t, 4096, 2768);
    transpose_cvt<<<dim3(2048, 16), 256, 0, stream>>>(lw1, lw1t, 65536, 512);

    // 1) xih = emb[q] @ w_ih^T + b_ih + b_hh via MFMA, laid out (S,B,4H)
    xih_mfma<<<dim3(80, 16), 256, 0, stream>>>(questions, embb, w_ihb, b_ih, b_hh, xih);

    // 2) all 20 LSTM steps in ONE persistent batch-parallel MFMA kernel -> h0b bf16
    lstm_all<<<16, 256, 0, stream>>>(xih, whib, wlob, h0b);

    // 3) hyper-MLP via bf16 MFMA split-K GEMMs (128x128 tile, global_load_lds)
    mfma128<<<dim3(2, 8, 4),  256, 0, stream>>>(h0b, w1t, accA, 256, 1024, 256, 64);
    ep_lrelu_bf16<<<1024, 256, 0, stream>>>(accA, hb1, h1b, 256, 1024);
    mfma128<<<dim3(2, 32, 4), 256, 0, stream>>>(h1b, w2t, accB, 256, 4096, 1024, 256);
    ep_lrelu_bf16<<<4096, 256, 0, stream>>>(accB, hb2, h2b, 256, 4096);
    mfma128<<<dim3(2, 22, 8), 256, 0, stream>>>(h2b, w3t, accC, 256, 2768, 4096, 512);
    ep_bias_f32<<<2768, 256, 0, stream>>>(accC, hb3, allw, 256, 2768);

    // 4) fused conv1+conv2 via MFMA tap-pair implicit GEMM -> bf16
    conv_fused_mfma<<<dim3(8, 256), 256, 0, stream>>>(images, allw, c2out);

    // 5) lin1 via bf16 MFMA split-K: 256x512, K=65536, splits=64 (512 blocks, 16 iters)
    mfma128<<<dim3(2, 4, 64), 256, 0, stream>>>(c2out, lw1t, acc1, 256, 512, 65536, 1024);
    bias_relu<<<512, 256, 0, stream>>>(acc1, lb1, l1out, 256, 512);

    // 6) lin2+lin3 fused -> out (256,2)
    lin23<<<256, 64, 0, stream>>>(l1out, lw2, lb2, lw3, lb3, out);
}

// Round 3
// 767.597 us; speedup vs baseline: 1.7815x; 1.7815x over previous
//
#include <hip/hip_runtime.h>
#include <hip/hip_bf16.h>
#include <math.h>

// Problem constants
constexpr int kB = 256, kS = 20, kE = 128, kH = 256;
constexpr int kTotalW = 2768;           // 432+16 + 2304+16
constexpr float kSlope = 1.0f / 5.5f;

typedef __bf16 bf16x8 __attribute__((ext_vector_type(8)));
typedef float  floatx4 __attribute__((ext_vector_type(4)));

// ---------------------------------------------------------------------------
// zero-fill (ws is poisoned 0xAA every call)
__global__ void zero_f32(float* __restrict__ p, int n) {
    for (int i = blockIdx.x * blockDim.x + threadIdx.x; i < n; i += gridDim.x * blockDim.x)
        p[i] = 0.f;
}

// rowmajor fp32 -> bf16 (RNE)
__global__ void cvt_bf16(const float* __restrict__ in, __bf16* __restrict__ out, int n) {
    for (int i = blockIdx.x * blockDim.x + threadIdx.x; i < n; i += gridDim.x * blockDim.x)
        out[i] = (__bf16)in[i];
}

// fp32 -> bf16 hi + bf16 lo residual (compensated split for LSTM recurrence)
__global__ void wsplit_bf16(const float* __restrict__ w, __bf16* __restrict__ whi,
                            __bf16* __restrict__ wlo, int n) {
    for (int i = blockIdx.x * blockDim.x + threadIdx.x; i < n; i += gridDim.x * blockDim.x) {
        float v = w[i];
        __bf16 hi = (__bf16)v;
        whi[i] = hi;
        wlo[i] = (__bf16)(v - (float)hi);
    }
}

// W (K x N fp32, row-major) -> Wt (N x K bf16, row-major). grid (K/32, ceil(N/32)), block 256.
__global__ __launch_bounds__(256) void transpose_cvt(
    const float* __restrict__ W, __bf16* __restrict__ Wt, int K, int N) {
    __shared__ float t[32][33];
    const int k0 = blockIdx.x * 32, n0 = blockIdx.y * 32;
    const int tx = threadIdx.x & 31, ty = threadIdx.x >> 5;   // 32 x 8
#pragma unroll
    for (int j = 0; j < 32; j += 8) {
        int n = n0 + tx, k = k0 + ty + j;
        t[ty + j][tx] = (n < N) ? W[(size_t)k * N + n] : 0.f;
    }
    __syncthreads();
#pragma unroll
    for (int j = 0; j < 32; j += 8) {
        int n = n0 + ty + j, k = k0 + tx;
        if (n < N) Wt[(size_t)n * K + k] = (__bf16)t[tx][ty + j];
    }
}

// ---------------------------------------------------------------------------
// async 16B global -> LDS (direct-to-LDS DMA; dest = wave-uniform base + lane*16)
__device__ __forceinline__ void gload16(const __bf16* g, __bf16* l) {
    __builtin_amdgcn_global_load_lds(
        (const __attribute__((address_space(1))) void*)g,
        (__attribute__((address_space(3))) void*)l, 16, 0, 0);
}

// ---------------------------------------------------------------------------
// bf16 MFMA split-K GEMM, m97 structure: 128x128 tile, BK=64, global_load_lds
// width-16 staging, single-buffer 2-barrier K-loop.
// Cacc(M,N fp32, pre-zeroed) += A(MxK bf16) @ Bt(NxK bf16)^T.
// 4 waves in a 2x2 grid, each wave owns a 64x64 sub-tile (acc[4][4] of 16x16).
// Fragment layouts (verified): A/B [outer=lane&15][k=(lane>>4)*8+j],
// C/D col=lane&15, row=(lane>>4)*4+reg.
// LDS linear [128][64] bf16 (no pad: global_load_lds needs contiguous dest).
// N not multiple of 128 handled by clamping B gather row (dup reads, garbage
// acc columns never stored). M, K must be multiples of 128/64 (true here).
__global__ __launch_bounds__(256) void mfma128(
    const __bf16* __restrict__ A, const __bf16* __restrict__ Bt,
    float* __restrict__ Cacc, int M, int N, int K, int Kchunk) {
    __shared__ __bf16 As[128 * 64];
    __shared__ __bf16 Bs[128 * 64];
    const int m0 = blockIdx.x * 128, n0 = blockIdx.y * 128;
    const int kbeg = blockIdx.z * Kchunk, kend = kbeg + Kchunk;
    const int tid = threadIdx.x, lane = tid & 63, wave = tid >> 6;
    const int wr = (wave >> 1) * 64, wc = (wave & 1) * 64;
    const int srow = lane >> 3, scol = (lane & 7) * 8;   // staging: lane -> (row, 16B seg)
    const int lrow = lane & 15, lk = (lane >> 4) * 8;    // frag read offsets
    floatx4 acc[4][4] = {};

    for (int k0 = kbeg; k0 < kend; k0 += 64) {
        // stage A/B 128x64 tiles: 8 chunks/wave, 1 KiB (8 rows) each, direct to LDS
#pragma unroll
        for (int c = 0; c < 4; ++c) {
            const int ch = wave * 4 + c;           // chunk 0..15 -> rows ch*8..ch*8+7
            const int rr = ch * 8 + srow;
            gload16(A + (size_t)(m0 + rr) * K + k0 + scol, &As[ch * 512]);
            int nr = n0 + rr; if (nr > N - 1) nr = N - 1;
            gload16(Bt + (size_t)nr * K + k0 + scol, &Bs[ch * 512]);
        }
        __syncthreads();                            // drains vmcnt -> tiles ready
#pragma unroll
        for (int ks = 0; ks < 2; ++ks) {
            bf16x8 af[4], bfv[4];
#pragma unroll
            for (int m = 0; m < 4; ++m)
                af[m] = *(const bf16x8*)&As[(wr + m * 16 + lrow) * 64 + ks * 32 + lk];
#pragma unroll
            for (int n = 0; n < 4; ++n)
                bfv[n] = *(const bf16x8*)&Bs[(wc + n * 16 + lrow) * 64 + ks * 32 + lk];
#pragma unroll
            for (int m = 0; m < 4; ++m)
#pragma unroll
                for (int n = 0; n < 4; ++n)
                    acc[m][n] = __builtin_amdgcn_mfma_f32_16x16x32_bf16(
                        af[m], bfv[n], acc[m][n], 0, 0, 0);
        }
        __syncthreads();
    }
    const int col = lane & 15, rq = (lane >> 4) * 4;
#pragma unroll
    for (int m = 0; m < 4; ++m)
#pragma unroll
        for (int n = 0; n < 4; ++n)
#pragma unroll
            for (int r = 0; r < 4; ++r) {
                int gm = m0 + wr + m * 16 + rq + r, gn = n0 + wc + n * 16 + col;
                if (gn < N) atomicAdd(&Cacc[(size_t)gm * N + gn], acc[m][n][r]);
            }
}

// epilogues: bias + leaky-relu -> bf16 (feeds next MFMA GEMM) / bias only -> fp32
__global__ void ep_lrelu_bf16(const float* __restrict__ acc, const float* __restrict__ bias,
                              __bf16* __restrict__ out, int M, int N) {
    int i = blockIdx.x * blockDim.x + threadIdx.x;
    if (i < M * N) {
        float v = acc[i] + bias[i % N];
        out[i] = (__bf16)(v > 0.f ? v : v * kSlope);
    }
}
__global__ void ep_bias_f32(const float* __restrict__ acc, const float* __restrict__ bias,
                            float* __restrict__ out, int M, int N) {
    int i = blockIdx.x * blockDim.x + threadIdx.x;
    if (i < M * N) out[i] = acc[i] + bias[i % N];
}

// ---------------------------------------------------------------------------
// xih via MFMA: xih[(s*B+b)*4H + n] = embb[q[b,s]] . w_ihb[n,:] + b_ih[n] + b_hh[n]
// A rows gathered via qs; w_ihb (4H x E) row-major == Bt layout. grid (80,16).
__global__ __launch_bounds__(256) void xih_mfma(
    const int* __restrict__ questions, const __bf16* __restrict__ embb,
    const __bf16* __restrict__ w_ihb, const float* __restrict__ b_ih,
    const float* __restrict__ b_hh, float* __restrict__ xih) {
    __shared__ __bf16 As[64][72];
    __shared__ __bf16 Bs[64][72];
    __shared__ int qs[64];
    const int m0 = blockIdx.x * 64, n0 = blockIdx.y * 64;
    const int tid = threadIdx.x, lane = tid & 63, wave = tid >> 6;
    if (tid < 64) {
        int m = m0 + tid;
        qs[tid] = questions[(m % kB) * kS + (m / kB)];
    }
    __syncthreads();
    floatx4 acc[4] = {};
    for (int k0 = 0; k0 < kE; k0 += 64) {
        for (int i = tid; i < 512; i += 256) {
            int r = i >> 3, seg = i & 7;
            *(uint4*)(&As[r][seg * 8]) =
                *(const uint4*)(embb + (size_t)qs[r] * kE + k0 + seg * 8);
        }
        for (int i = tid; i < 512; i += 256) {
            int r = i >> 3, seg = i & 7;
            *(uint4*)(&Bs[r][seg * 8]) =
                *(const uint4*)(w_ihb + (size_t)(n0 + r) * kE + k0 + seg * 8);
        }
        __syncthreads();
#pragma unroll
        for (int ks = 0; ks < 2; ++ks) {
            bf16x8 af = *(const bf16x8*)(&As[wave * 16 + (lane & 15)][ks * 32 + (lane >> 4) * 8]);
#pragma unroll
            for (int nb = 0; nb < 4; ++nb) {
                bf16x8 bfr = *(const bf16x8*)(&Bs[nb * 16 + (lane & 15)][ks * 32 + (lane >> 4) * 8]);
                acc[nb] = __builtin_amdgcn_mfma_f32_16x16x32_bf16(af, bfr, acc[nb], 0, 0, 0);
            }
        }
        __syncthreads();
    }
    const int col = lane & 15, rq = (lane >> 4) * 4;
#pragma unroll
    for (int nb = 0; nb < 4; ++nb)
#pragma unroll
        for (int r = 0; r < 4; ++r) {
            int m = m0 + wave * 16 + rq + r, n = n0 + nb * 16 + col;
            xih[(size_t)m * 1024 + n] = acc[nb][r] + b_ih[n] + b_hh[n];
        }
}

// ---------------------------------------------------------------------------
// One LSTM step via MFMA, gate-fused. Grid (4 batch-groups, 8 j-groups), 256 thr.
// Block: batch rows m0..m0+63, hidden cols j0..j0+31, ALL 4 gates (B rows
// g*256+j0+jj staged at LDS row (g*2+jt)*16+r -> n-frag nf = g*2+jt).
// gates = xih_t + h@W^T with compensated bf16 split (hi*hi + lo*hi + hi*lo).
// h carried as bf16 hi+lo ping-pong; c fp32 in-place (each (b,j) owned by
// exactly one block). first=1: h=c=0 -> skip K-loop entirely.
// Wave wv owns batch rows m0+wv*16..+15 (A-frag outer), all 8 n-frags.
__global__ __launch_bounds__(256) void lstm_step_mfma(
    const float* __restrict__ xih_t,    // (256,1024)
    const __bf16* __restrict__ whi,     // (1024,256)
    const __bf16* __restrict__ wlo,     // (1024,256)
    const __bf16* __restrict__ hhi_p, const __bf16* __restrict__ hlo_p,
    float* __restrict__ c,              // (256,256) in-place
    __bf16* __restrict__ hhi_n, __bf16* __restrict__ hlo_n,
    int first) {
    __shared__ __bf16 Ah[64 * 64];      // h hi tile
    __shared__ __bf16 Al[64 * 64];      // h lo tile
    __shared__ __bf16 Bh[128 * 64];     // W hi (4 gates x 32 j)
    __shared__ __bf16 Bl[128 * 64];     // W lo
    const int m0 = blockIdx.x * 64, j0 = blockIdx.y * 32;
    const int tid = threadIdx.x, lane = tid & 63, wv = tid >> 6;
    const int srow = lane >> 3, scol = (lane & 7) * 8;
    const int lrow = lane & 15, lk = (lane >> 4) * 8;
    const int col = lane & 15, rq = (lane >> 4) * 4;

    floatx4 acc[8];                     // nf = g*2+jt
#pragma unroll
    for (int nf = 0; nf < 8; ++nf) {
        int g = nf >> 1, jt = nf & 1;
        int n = g * 256 + j0 + jt * 16 + col;
#pragma unroll
        for (int r = 0; r < 4; ++r)
            acc[nf][r] = xih_t[(size_t)(m0 + wv * 16 + rq + r) * 1024 + n];
    }
    if (!first) {
        for (int k0 = 0; k0 < kH; k0 += 64) {
#pragma unroll
            for (int cc = 0; cc < 2; ++cc) {        // A hi/lo: 8 chunks each, 2/wave
                int ch = wv * 2 + cc, r = ch * 8 + srow;
                gload16(hhi_p + (size_t)(m0 + r) * kH + k0 + scol, &Ah[ch * 512]);
                gload16(hlo_p + (size_t)(m0 + r) * kH + k0 + scol, &Al[ch * 512]);
            }
#pragma unroll
            for (int cc = 0; cc < 4; ++cc) {        // B hi/lo: 16 chunks each, 4/wave
                int ch = wv * 4 + cc, bn = ch * 8 + srow;
                size_t wrow = (size_t)((bn >> 5) * 256 + j0 + (bn & 31));
                gload16(whi + wrow * kH + k0 + scol, &Bh[ch * 512]);
                gload16(wlo + wrow * kH + k0 + scol, &Bl[ch * 512]);
            }
            __syncthreads();
#pragma unroll
            for (int ks = 0; ks < 2; ++ks) {
                bf16x8 ah = *(const bf16x8*)&Ah[(wv * 16 + lrow) * 64 + ks * 32 + lk];
                bf16x8 al = *(const bf16x8*)&Al[(wv * 16 + lrow) * 64 + ks * 32 + lk];
#pragma unroll
                for (int nf = 0; nf < 8; ++nf) {
                    bf16x8 bh = *(const bf16x8*)&Bh[(nf * 16 + lrow) * 64 + ks * 32 + lk];
                    bf16x8 bl = *(const bf16x8*)&Bl[(nf * 16 + lrow) * 64 + ks * 32 + lk];
                    acc[nf] = __builtin_amdgcn_mfma_f32_16x16x32_bf16(ah, bh, acc[nf], 0, 0, 0);
                    acc[nf] = __builtin_amdgcn_mfma_f32_16x16x32_bf16(al, bh, acc[nf], 0, 0, 0);
                    acc[nf] = __builtin_amdgcn_mfma_f32_16x16x32_bf16(ah, bl, acc[nf], 0, 0, 0);
                }
            }
            __syncthreads();
        }
    }
    // gate-fused epilogue: this thread owns 8 (b,j) pairs with all 4 gates
#pragma unroll
    for (int jt = 0; jt < 2; ++jt)
#pragma unroll
        for (int r = 0; r < 4; ++r) {
            int b = m0 + wv * 16 + rq + r, j = j0 + jt * 16 + col;
            float gi = acc[0 * 2 + jt][r], gf = acc[1 * 2 + jt][r];
            float gg = acc[2 * 2 + jt][r], go = acc[3 * 2 + jt][r];
            float i_ = 1.f / (1.f + expf(-gi));
            float f_ = 1.f / (1.f + expf(-gf));
            float g_ = tanhf(gg);
            float o_ = 1.f / (1.f + expf(-go));
            float cp = first ? 0.f : c[(size_t)b * kH + j];
            float cn = f_ * cp + i_ * g_;
            c[(size_t)b * kH + j] = cn;
            float h = o_ * tanhf(cn);
            __bf16 hi = (__bf16)h;
            hhi_n[(size_t)b * kH + j] = hi;
            hlo_n[(size_t)b * kH + j] = (__bf16)(h - (float)hi);
        }
}

__global__ void bias_relu(const float* __restrict__ acc, const float* __restrict__ bias,
                          float* __restrict__ out, int M, int N) {
    int i = blockIdx.x * blockDim.x + threadIdx.x;
    if (i < M * N) {
        int n = i % N;
        out[i] = fmaxf(acc[i] + bias[n], 0.f);
    }
}

// ---------------------------------------------------------------------------
// MFMA tap-pair fused conv1(3->16) + conv2(16->16), 3x3, pad 1, no act between.
// One block = one sample x one 8-row output slab. Both convs use the SAME
// decomposition: K=32 MFMA covers tap-pair p (k<16 -> tap 2p, k>=16 -> tap 2p+1);
// A[o][k] holds the weights (zeros for c>=Cin or tap 9), B read from channel-
// contiguous LDS [row][col][ch16] (32B col stride, 16B-aligned b128 reads).
// Zero padding (image border AND conv2's padding of conv1 output) comes from
// the LDS memset: invalid rows are simply skipped.
constexpr int ICH = 16;   // img_s channel stride (bf16)
constexpr int MCH = 16;   // mid_s channel stride (bf16)

__global__ __launch_bounds__(256) void conv_fused_mfma(
    const float* __restrict__ img,     // (B,3,64,64)
    const float* __restrict__ all_w,   // (B,2768)
    __bf16* __restrict__ out) {        // (B,16,64,64) bf16
    const int b = blockIdx.y;
    const int y0 = blockIdx.x * 8;
    __shared__ __align__(16) __bf16 w1a[5 * 16 * 32];         // [pair][o][k]
    __shared__ __align__(16) __bf16 w2a[5 * 16 * 32];         // [pair][o][k]
    __shared__ float bias_s[32];                              // conv1 | conv2 bias
    __shared__ __align__(16) __bf16 img_s[12 * 66 * ICH];     // rows gy=y0-2..y0+9
    __shared__ __align__(16) __bf16 mid_s[10 * 66 * MCH];     // rows gy=y0-1..y0+8

    const int tid = threadIdx.x, lane = tid & 63, wave = tid >> 6;
    const float* wb = all_w + (size_t)b * kTotalW;

    // ---- phase A0: memset both LDS tiles (halo zeros + pad channels), weights ----
    for (int i = tid; i < 12 * 66 * ICH / 8; i += 256)
        ((uint4*)img_s)[i] = make_uint4(0u, 0u, 0u, 0u);
    for (int i = tid; i < 10 * 66 * MCH / 8; i += 256)
        ((uint4*)mid_s)[i] = make_uint4(0u, 0u, 0u, 0u);
    for (int i = tid; i < 2560; i += 256) {      // w1a: k=half*16+c, t=2p+half
        int p = i >> 9, rem = i & 511, o = rem >> 5, k = rem & 31;
        int half = k >> 4, c = k & 15, t = 2 * p + half;
        w1a[i] = (__bf16)((c < 3 && t < 9) ? wb[o * 27 + c * 9 + t] : 0.f);
    }
    for (int i = tid; i < 2560; i += 256) {      // w2a
        int p = i >> 9, rem = i & 511, o = rem >> 5, k = rem & 31;
        int half = k >> 4, c = k & 15, t = 2 * p + half;
        w2a[i] = (__bf16)((t < 9) ? wb[448 + (o * 16 + c) * 9 + t] : 0.f);
    }
    if (tid < 16) bias_s[tid] = wb[432 + tid];
    else if (tid < 32) bias_s[tid] = wb[2752 + (tid - 16)];
    __syncthreads();

    // ---- phase A1: fill real image pixels (coalesced global reads) ----
    for (int i = tid; i < 3 * 12 * 64; i += 256) {
        int c = i / 768, rem = i - c * 768, r = rem >> 6, x = rem & 63;
        int gy = y0 - 2 + r;
        if (gy >= 0 && gy < 64)
            img_s[(r * 66 + (x + 1)) * ICH + c] =
                (__bf16)img[(((size_t)b * 3 + c) << 12) + (gy << 6) + x];
    }
    __syncthreads();

    // per-lane fragment constants (shared by both convs)
    const int n = lane & 15, half = lane >> 5;
    const int c0 = ((lane >> 4) & 1) * 8, o0 = (lane >> 4) * 4;
    int dy_[5], dx_[5];
#pragma unroll
    for (int p = 0; p < 5; ++p) {
        int t = 2 * p + half;
        dy_[p] = (t < 9) ? t / 3 : 0;
        dx_[p] = (t < 9) ? t % 3 : 0;
    }
    bf16x8 a1[5], a2[5];
#pragma unroll
    for (int p = 0; p < 5; ++p) {
        a1[p] = *(const bf16x8*)&w1a[p * 512 + n * 32 + (lane >> 4) * 8];
        a2[p] = *(const bf16x8*)&w2a[p * 512 + n * 32 + (lane >> 4) * 8];
    }

    // ---- phase B: conv1, 40 tiles (10 mid-rows x 4 x-tiles), 10 per wave ----
#pragma unroll
    for (int ti = 0; ti < 10; ++ti) {
        int tile = wave * 10 + ti;
        int rr = tile >> 2, xt = (tile & 3) * 16;
        int gy = y0 - 1 + rr;                    // mid row's global y
        if (gy >= 0 && gy < 64) {                // else: stays zero (conv2's padding)
            floatx4 acc = {};
#pragma unroll
            for (int p = 0; p < 5; ++p) {
                bf16x8 bfr = *(const bf16x8*)
                    &img_s[((rr + dy_[p]) * 66 + (xt + n + dx_[p])) * ICH + c0];
                acc = __builtin_amdgcn_mfma_f32_16x16x32_bf16(a1[p], bfr, acc, 0, 0, 0);
            }
            union { short4 s4; __bf16 h[4]; } u;
#pragma unroll
            for (int q = 0; q < 4; ++q) u.h[q] = (__bf16)(acc[q] + bias_s[o0 + q]);
            *(short4*)&mid_s[(rr * 66 + (xt + n + 1)) * MCH + o0] = u.s4;
        }
    }
    __syncthreads();

    // ---- phase C: conv2, 32 tiles (8 rows x 4 x-tiles), 8 per wave ----
#pragma unroll
    for (int ti = 0; ti < 8; ++ti) {
        int tile = wave * 8 + ti;
        int rr = tile >> 2, xt = (tile & 3) * 16;
        floatx4 acc = {};
#pragma unroll
        for (int p = 0; p < 5; ++p) {
            bf16x8 bfr = *(const bf16x8*)
                &mid_s[((rr + dy_[p]) * 66 + (xt + n + dx_[p])) * MCH + c0];
            acc = __builtin_amdgcn_mfma_f32_16x16x32_bf16(a2[p], bfr, acc, 0, 0, 0);
        }
        int gy = y0 + rr, gx = xt + n;
#pragma unroll
        for (int q = 0; q < 4; ++q)
            out[(((size_t)b * 16 + o0 + q) * 64 + gy) * 64 + gx] =
                (__bf16)(acc[q] + bias_s[16 + o0 + q]);
    }
}

// ---------------------------------------------------------------------------
// Fused lin2+lin3: out(256,2). grid B, block 64.
__global__ __launch_bounds__(64) void lin23(
    const float* __restrict__ l1out,
    const float* __restrict__ lw2, const float* __restrict__ lb2,
    const float* __restrict__ lw3, const float* __restrict__ lb3,
    float* __restrict__ out) {
    const int b = blockIdx.x, j = threadIdx.x;
    __shared__ float row[512];
    __shared__ float s[64];
    for (int i = j; i < 512; i += 64) row[i] = l1out[(size_t)b * 512 + i];
    __syncthreads();
    float acc = lb2[j];
    for (int k = 0; k < 512; ++k) acc += row[k] * lw2[(size_t)k * 64 + j];
    s[j] = fmaxf(acc, 0.f);
    __syncthreads();
    if (j < 2) {
        float o = lb3[j];
        for (int k = 0; k < 64; ++k) o += s[k] * lw3[(size_t)k * 2 + j];
        out[(size_t)b * 2 + j] = o;
    }
}

// ---------------------------------------------------------------------------
extern "C" void kernel_launch(void* const* d_in, const int* in_sizes, int n_in,
                              void* d_out, int out_size, void* d_ws, size_t ws_size,
                              hipStream_t stream) {
    const int* questions = (const int*)d_in[0];
    const float* images  = (const float*)d_in[1];
    const float* emb     = (const float*)d_in[2];
    const float* w_ih    = (const float*)d_in[3];
    const float* w_hh    = (const float*)d_in[4];
    const float* b_ih    = (const float*)d_in[5];
    const float* b_hh    = (const float*)d_in[6];
    const float* hw1     = (const float*)d_in[7];
    const float* hb1     = (const float*)d_in[8];
    const float* hw2     = (const float*)d_in[9];
    const float* hb2     = (const float*)d_in[10];
    const float* hw3     = (const float*)d_in[11];
    const float* hb3     = (const float*)d_in[12];
    const float* lw1     = (const float*)d_in[13];
    const float* lb1     = (const float*)d_in[14];
    const float* lw2     = (const float*)d_in[15];
    const float* lb2     = (const float*)d_in[16];
    const float* lw3     = (const float*)d_in[17];
    const float* lb3     = (const float*)d_in[18];
    float* out = (float*)d_out;

    char* ws = (char*)d_ws;
    size_t off = 0;
    auto alloc = [&](size_t nbytes) -> void* {
        void* p = (void*)(ws + off);
        off += (nbytes + 255) & ~(size_t)255;
        return p;
    };
    // big (64MB) timeline (single stream, strictly ordered):
    //   [0..20MB)  xih fp32            (dead after LSTM)
    //   [24..47MB) w3t bf16            (dead after hw3 MFMA GEMM)
    //   [0..32MB)  conv out bf16       (written by conv_fused_mfma, after both above dead)
    float*  big   = (float*)alloc(64ull << 20);
    __bf16* lw1t  = (__bf16*)alloc((size_t)512 * 65536 * 2);   // lw1^T bf16
    __bf16* w1t   = (__bf16*)alloc((size_t)1024 * 256 * 2);    // hw1^T bf16
    __bf16* w2t   = (__bf16*)alloc((size_t)4096 * 1024 * 2);   // hw2^T bf16
    __bf16* embb  = (__bf16*)alloc((size_t)10000 * kE * 2);    // emb bf16
    __bf16* w_ihb = (__bf16*)alloc((size_t)1024 * kE * 2);     // w_ih bf16 (already (N,K))
    __bf16* whib  = (__bf16*)alloc((size_t)1024 * kH * 2);     // w_hh bf16 hi
    __bf16* wlob  = (__bf16*)alloc((size_t)1024 * kH * 2);     // w_hh bf16 lo residual
    __bf16* hhi0  = (__bf16*)alloc((size_t)kB * kH * 2);       // h hi ping-pong
    __bf16* hlo0  = (__bf16*)alloc((size_t)kB * kH * 2);
    __bf16* hhi1  = (__bf16*)alloc((size_t)kB * kH * 2);
    __bf16* hlo1  = (__bf16*)alloc((size_t)kB * kH * 2);
    float*  cbuf  = (float*)alloc((size_t)kB * kH * sizeof(float));
    __bf16* h1b   = (__bf16*)alloc((size_t)kB * 1024 * 2);
    __bf16* h2b   = (__bf16*)alloc((size_t)kB * 4096 * 2);
    // contiguous fp32 accumulators (zeroed in one kernel): hw1 | hw2 | hw3 | lin1
    float*  accz  = (float*)alloc((size_t)kB * (1024 + 4096 + 2768 + 512) * sizeof(float));
    float*  accA  = accz;
    float*  accB  = accA + (size_t)kB * 1024;
    float*  accC  = accB + (size_t)kB * 4096;
    float*  acc1  = accC + (size_t)kB * 2768;
    float*  allw  = (float*)alloc((size_t)kB * kTotalW * sizeof(float));
    float*  l1out = (float*)alloc((size_t)kB * 512 * sizeof(float));

    float*  xih    = big;
    __bf16* c2out  = (__bf16*)big;
    __bf16* w3t    = (__bf16*)((char*)big + (24ull << 20));    // 2768 x 4096 bf16
    __bf16* hh[2]  = {hhi0, hhi1};
    __bf16* hl[2]  = {hlo0, hlo1};
    const int nACC = kB * (1024 + 4096 + 2768 + 512);
    zero_f32<<<512, 256, 0, stream>>>(accz, nACC);

    // weight converts/transposes (regions disjoint from their concurrent readers/writers)
    cvt_bf16<<<1280, 256, 0, stream>>>(emb, embb, 10000 * kE);
    cvt_bf16<<<128, 256, 0, stream>>>(w_ih, w_ihb, 1024 * kE);
    wsplit_bf16<<<256, 256, 0, stream>>>(w_hh, whib, wlob, 1024 * kH);
    transpose_cvt<<<dim3(8, 32),   256, 0, stream>>>(hw1, w1t, 256, 1024);
    transpose_cvt<<<dim3(32, 128), 256, 0, stream>>>(hw2, w2t, 1024, 4096);
    transpose_cvt<<<dim3(128, 87), 256, 0, stream>>>(hw3, w3t, 4096, 2768);
    transpose_cvt<<<dim3(2048, 16), 256, 0, stream>>>(lw1, lw1t, 65536, 512);

    // 1) xih = emb[q] @ w_ih^T + b_ih + b_hh via MFMA, laid out (S,B,4H)
    xih_mfma<<<dim3(80, 16), 256, 0, stream>>>(questions, embb, w_ihb, b_ih, b_hh, xih);

    // 2) 20 LSTM steps, MFMA + gate-fused epilogue, h as bf16 hi/lo ping-pong
    for (int t = 0; t < kS; ++t) {
        lstm_step_mfma<<<dim3(4, 8), 256, 0, stream>>>(
            xih + (size_t)t * kB * 1024, whib, wlob,
            hh[t & 1], hl[t & 1], cbuf, hh[(t + 1) & 1], hl[(t + 1) & 1], t == 0);
    }
    __bf16* h0b = hh[0];   // t=19 writes buffer 0; bf16 hi IS (bf16)h

    // 3) hyper-MLP via bf16 MFMA split-K GEMMs (128x128 tile, global_load_lds)
    mfma128<<<dim3(2, 8, 4),  256, 0, stream>>>(h0b, w1t, accA, 256, 1024, 256, 64);
    ep_lrelu_bf16<<<1024, 256, 0, stream>>>(accA, hb1, h1b, 256, 1024);
    mfma128<<<dim3(2, 32, 4), 256, 0, stream>>>(h1b, w2t, accB, 256, 4096, 1024, 256);
    ep_lrelu_bf16<<<4096, 256, 0, stream>>>(accB, hb2, h2b, 256, 4096);
    mfma128<<<dim3(2, 22, 8), 256, 0, stream>>>(h2b, w3t, accC, 256, 2768, 4096, 512);
    ep_bias_f32<<<2768, 256, 0, stream>>>(accC, hb3, allw, 256, 2768);

    // 4) fused conv1+conv2 via MFMA tap-pair implicit GEMM -> bf16
    conv_fused_mfma<<<dim3(8, 256), 256, 0, stream>>>(images, allw, c2out);

    // 5) lin1 via bf16 MFMA split-K: 256x512, K=65536, splits=64 (512 blocks, 16 iters)
    mfma128<<<dim3(2, 4, 64), 256, 0, stream>>>(c2out, lw1t, acc1, 256, 512, 65536, 1024);
    bias_relu<<<512, 256, 0, stream>>>(acc1, lb1, l1out, 256, 512);

    // 6) lin2+lin3 fused -> out (256,2)
    lin23<<<256, 64, 0, stream>>>(l1out, lw2, lb2, lw3, lb3, out);
}

// Round 4
// 762.553 us; speedup vs baseline: 1.7933x; 1.0066x over previous
//
#include <hip/hip_runtime.h>
#include <hip/hip_bf16.h>
#include <math.h>

// Problem constants
constexpr int kB = 256, kS = 20, kE = 128, kH = 256;
constexpr int kTotalW = 2768;           // 432+16 + 2304+16
constexpr float kSlope = 1.0f / 5.5f;

typedef __bf16 bf16x8 __attribute__((ext_vector_type(8)));
typedef float  floatx4 __attribute__((ext_vector_type(4)));

// ---------------------------------------------------------------------------
// zero-fill (ws is poisoned 0xAA every call)
__global__ void zero_f32(float* __restrict__ p, int n) {
    for (int i = blockIdx.x * blockDim.x + threadIdx.x; i < n; i += gridDim.x * blockDim.x)
        p[i] = 0.f;
}

// rowmajor fp32 -> bf16 (RNE)
__global__ void cvt_bf16(const float* __restrict__ in, __bf16* __restrict__ out, int n) {
    for (int i = blockIdx.x * blockDim.x + threadIdx.x; i < n; i += gridDim.x * blockDim.x)
        out[i] = (__bf16)in[i];
}

// fp32 -> bf16 hi + bf16 lo residual (compensated split for LSTM recurrence)
__global__ void wsplit_bf16(const float* __restrict__ w, __bf16* __restrict__ whi,
                            __bf16* __restrict__ wlo, int n) {
    for (int i = blockIdx.x * blockDim.x + threadIdx.x; i < n; i += gridDim.x * blockDim.x) {
        float v = w[i];
        __bf16 hi = (__bf16)v;
        whi[i] = hi;
        wlo[i] = (__bf16)(v - (float)hi);
    }
}

// W (K x N fp32, row-major) -> Wt (N x K bf16, row-major). grid (K/32, ceil(N/32)), block 256.
__global__ __launch_bounds__(256) void transpose_cvt(
    const float* __restrict__ W, __bf16* __restrict__ Wt, int K, int N) {
    __shared__ float t[32][33];
    const int k0 = blockIdx.x * 32, n0 = blockIdx.y * 32;
    const int tx = threadIdx.x & 31, ty = threadIdx.x >> 5;   // 32 x 8
#pragma unroll
    for (int j = 0; j < 32; j += 8) {
        int n = n0 + tx, k = k0 + ty + j;
        t[ty + j][tx] = (n < N) ? W[(size_t)k * N + n] : 0.f;
    }
    __syncthreads();
#pragma unroll
    for (int j = 0; j < 32; j += 8) {
        int n = n0 + ty + j, k = k0 + tx;
        if (n < N) Wt[(size_t)n * K + k] = (__bf16)t[tx][ty + j];
    }
}

// ---------------------------------------------------------------------------
// async 16B global -> LDS (direct-to-LDS DMA; dest = wave-uniform base + lane*16)
__device__ __forceinline__ void gload16(const __bf16* g, __bf16* l) {
    __builtin_amdgcn_global_load_lds(
        (const __attribute__((address_space(1))) void*)g,
        (__attribute__((address_space(3))) void*)l, 16, 0, 0);
}

// ---------------------------------------------------------------------------
// bf16 MFMA split-K GEMM, m97 structure: 128x128 tile, BK=64, global_load_lds
// width-16 staging, single-buffer 2-barrier K-loop.
// Cacc(M,N fp32, pre-zeroed) += A(MxK bf16) @ Bt(NxK bf16)^T.
// 4 waves in a 2x2 grid, each wave owns a 64x64 sub-tile (acc[4][4] of 16x16).
// Fragment layouts (verified): A/B [outer=lane&15][k=(lane>>4)*8+j],
// C/D col=lane&15, row=(lane>>4)*4+reg.
__global__ __launch_bounds__(256) void mfma128(
    const __bf16* __restrict__ A, const __bf16* __restrict__ Bt,
    float* __restrict__ Cacc, int M, int N, int K, int Kchunk) {
    __shared__ __bf16 As[128 * 64];
    __shared__ __bf16 Bs[128 * 64];
    const int m0 = blockIdx.x * 128, n0 = blockIdx.y * 128;
    const int kbeg = blockIdx.z * Kchunk, kend = kbeg + Kchunk;
    const int tid = threadIdx.x, lane = tid & 63, wave = tid >> 6;
    const int wr = (wave >> 1) * 64, wc = (wave & 1) * 64;
    const int srow = lane >> 3, scol = (lane & 7) * 8;   // staging: lane -> (row, 16B seg)
    const int lrow = lane & 15, lk = (lane >> 4) * 8;    // frag read offsets
    floatx4 acc[4][4] = {};

    for (int k0 = kbeg; k0 < kend; k0 += 64) {
#pragma unroll
        for (int c = 0; c < 4; ++c) {
            const int ch = wave * 4 + c;           // chunk 0..15 -> rows ch*8..ch*8+7
            const int rr = ch * 8 + srow;
            gload16(A + (size_t)(m0 + rr) * K + k0 + scol, &As[ch * 512]);
            int nr = n0 + rr; if (nr > N - 1) nr = N - 1;
            gload16(Bt + (size_t)nr * K + k0 + scol, &Bs[ch * 512]);
        }
        __syncthreads();                            // drains vmcnt -> tiles ready
#pragma unroll
        for (int ks = 0; ks < 2; ++ks) {
            bf16x8 af[4], bfv[4];
#pragma unroll
            for (int m = 0; m < 4; ++m)
                af[m] = *(const bf16x8*)&As[(wr + m * 16 + lrow) * 64 + ks * 32 + lk];
#pragma unroll
            for (int n = 0; n < 4; ++n)
                bfv[n] = *(const bf16x8*)&Bs[(wc + n * 16 + lrow) * 64 + ks * 32 + lk];
#pragma unroll
            for (int m = 0; m < 4; ++m)
#pragma unroll
                for (int n = 0; n < 4; ++n)
                    acc[m][n] = __builtin_amdgcn_mfma_f32_16x16x32_bf16(
                        af[m], bfv[n], acc[m][n], 0, 0, 0);
        }
        __syncthreads();
    }
    const int col = lane & 15, rq = (lane >> 4) * 4;
#pragma unroll
    for (int m = 0; m < 4; ++m)
#pragma unroll
        for (int n = 0; n < 4; ++n)
#pragma unroll
            for (int r = 0; r < 4; ++r) {
                int gm = m0 + wr + m * 16 + rq + r, gn = n0 + wc + n * 16 + col;
                if (gn < N) atomicAdd(&Cacc[(size_t)gm * N + gn], acc[m][n][r]);
            }
}

// epilogues: bias + leaky-relu -> bf16 (feeds next MFMA GEMM) / bias only -> fp32
__global__ void ep_lrelu_bf16(const float* __restrict__ acc, const float* __restrict__ bias,
                              __bf16* __restrict__ out, int M, int N) {
    int i = blockIdx.x * blockDim.x + threadIdx.x;
    if (i < M * N) {
        float v = acc[i] + bias[i % N];
        out[i] = (__bf16)(v > 0.f ? v : v * kSlope);
    }
}
__global__ void ep_bias_f32(const float* __restrict__ acc, const float* __restrict__ bias,
                            float* __restrict__ out, int M, int N) {
    int i = blockIdx.x * blockDim.x + threadIdx.x;
    if (i < M * N) out[i] = acc[i] + bias[i % N];
}

// ---------------------------------------------------------------------------
// xih via MFMA: xih[(s*B+b)*4H + n] = embb[q[b,s]] . w_ihb[n,:] + b_ih[n] + b_hh[n]
__global__ __launch_bounds__(256) void xih_mfma(
    const int* __restrict__ questions, const __bf16* __restrict__ embb,
    const __bf16* __restrict__ w_ihb, const float* __restrict__ b_ih,
    const float* __restrict__ b_hh, float* __restrict__ xih) {
    __shared__ __bf16 As[64][72];
    __shared__ __bf16 Bs[64][72];
    __shared__ int qs[64];
    const int m0 = blockIdx.x * 64, n0 = blockIdx.y * 64;
    const int tid = threadIdx.x, lane = tid & 63, wave = tid >> 6;
    if (tid < 64) {
        int m = m0 + tid;
        qs[tid] = questions[(m % kB) * kS + (m / kB)];
    }
    __syncthreads();
    floatx4 acc[4] = {};
    for (int k0 = 0; k0 < kE; k0 += 64) {
        for (int i = tid; i < 512; i += 256) {
            int r = i >> 3, seg = i & 7;
            *(uint4*)(&As[r][seg * 8]) =
                *(const uint4*)(embb + (size_t)qs[r] * kE + k0 + seg * 8);
        }
        for (int i = tid; i < 512; i += 256) {
            int r = i >> 3, seg = i & 7;
            *(uint4*)(&Bs[r][seg * 8]) =
                *(const uint4*)(w_ihb + (size_t)(n0 + r) * kE + k0 + seg * 8);
        }
        __syncthreads();
#pragma unroll
        for (int ks = 0; ks < 2; ++ks) {
            bf16x8 af = *(const bf16x8*)(&As[wave * 16 + (lane & 15)][ks * 32 + (lane >> 4) * 8]);
#pragma unroll
            for (int nb = 0; nb < 4; ++nb) {
                bf16x8 bfr = *(const bf16x8*)(&Bs[nb * 16 + (lane & 15)][ks * 32 + (lane >> 4) * 8]);
                acc[nb] = __builtin_amdgcn_mfma_f32_16x16x32_bf16(af, bfr, acc[nb], 0, 0, 0);
            }
        }
        __syncthreads();
    }
    const int col = lane & 15, rq = (lane >> 4) * 4;
#pragma unroll
    for (int nb = 0; nb < 4; ++nb)
#pragma unroll
        for (int r = 0; r < 4; ++r) {
            int m = m0 + wave * 16 + rq + r, n = n0 + nb * 16 + col;
            xih[(size_t)m * 1024 + n] = acc[nb][r] + b_ih[n] + b_hh[n];
        }
}

// ---------------------------------------------------------------------------
// Persistent LSTM, all 20 steps in ONE kernel. Grid (4 batch-groups, 8 j-groups)
// = 32 blocks x 256 thr (1 block/CU via 144 KB LDS; empty in-order stream ->
// all co-resident). Block owns batch rows m0..m0+63 x hidden cols j0..j0+31,
// ALL 4 gates. W hi/lo slice (128 rows x 256 k = 128 KB) loaded into LDS ONCE,
// FRAGMENT-MAJOR ([nf][ks4][lane][8]: lane-contiguous 16B -> conflict-free
// ds_read_b128; scatter happens on the write side). Per step: h staged via
// gload16 per-64k chunk, 192 MFMA/wave (compensated bf16 split: hi*hi + lo*hi
// + hi*lo), gate epilogue with c in REGISTERS across all steps, h hi/lo
// ping-pong via global. Cross-block dep is only among the 8 blocks sharing a
// batch-slice -> per-mb monotonic spin barrier (threadfence + agent-scope
// atomics; release wb-L2, acquire inv -> cross-XCD safe).
__global__ __launch_bounds__(256, 1) void lstm_persist(
    const float* __restrict__ xih,    // (20,256,1024)
    const __bf16* __restrict__ whi,   // (1024,256)
    const __bf16* __restrict__ wlo,   // (1024,256)
    __bf16* __restrict__ hhi0, __bf16* __restrict__ hlo0,   // ping-pong buf 0
    __bf16* __restrict__ hhi1, __bf16* __restrict__ hlo1,   // ping-pong buf 1
    int* __restrict__ bar) {          // int[4], pre-zeroed
    __shared__ __bf16 Wh[128 * 256];  // 64 KB, frag-major
    __shared__ __bf16 Wl[128 * 256];  // 64 KB
    __shared__ __bf16 Ah[64 * 64];    // 8 KB, h hi tile (one 64-k chunk)
    __shared__ __bf16 Al[64 * 64];    // 8 KB
    const int mb = blockIdx.x, m0 = mb * 64, j0 = blockIdx.y * 32;
    const int tid = threadIdx.x, lane = tid & 63, wv = tid >> 6;
    const int srow = lane >> 3, scol = (lane & 7) * 8;
    const int lrow = lane & 15, lk = (lane >> 4) * 8;
    const int col = lane & 15, rq = (lane >> 4) * 4;

    // ---- load W slice into LDS, frag-major: elem(nf,ks4,l,e) =
    //      W[g*256+j0+jj][ks4*32+(l>>4)*8+e], nf=g*2+(jj>>4), l=((k>>3)&3)*16+(jj&15)
    for (int i = tid; i < 4096; i += 256) {
        int lrr = i >> 5, m8 = i & 31;                 // local row, 8-elem k chunk
        int g = lrr >> 5, jj = lrr & 31;
        int grow = g * 256 + j0 + jj;
        int nf = g * 2 + (jj >> 4), lr = jj & 15;
        int k = m8 * 8, ks4 = k >> 5, hi8 = (k >> 3) & 3;
        int dst = ((nf * 8 + ks4) * 64 + hi8 * 16 + lr) * 8;
        *(bf16x8*)&Wh[dst] = *(const bf16x8*)(whi + (size_t)grow * kH + k);
        *(bf16x8*)&Wl[dst] = *(const bf16x8*)(wlo + (size_t)grow * kH + k);
    }
    __syncthreads();

    float c_reg[2][4] = {};                            // [jt][r], persistent
    for (int t = 0; t < kS; ++t) {
        floatx4 acc[8];                                // nf = g*2+jt
        const float* xb = xih + (size_t)t * kB * 1024;
#pragma unroll
        for (int nf = 0; nf < 8; ++nf) {
            int g = nf >> 1, jt = nf & 1;
            int n = g * 256 + j0 + jt * 16 + col;
#pragma unroll
            for (int r = 0; r < 4; ++r)
                acc[nf][r] = xb[(size_t)(m0 + wv * 16 + rq + r) * 1024 + n];
        }
        if (t > 0) {
            const __bf16* Hh = (t & 1) ? hhi1 : hhi0;  // read buf = t&1
            const __bf16* Hl = (t & 1) ? hlo1 : hlo0;
            for (int k0 = 0; k0 < kH; k0 += 64) {
#pragma unroll
                for (int cc = 0; cc < 2; ++cc) {       // stage h 64x64 hi+lo
                    int ch = wv * 2 + cc, r = ch * 8 + srow;
                    gload16(Hh + (size_t)(m0 + r) * kH + k0 + scol, &Ah[ch * 512]);
                    gload16(Hl + (size_t)(m0 + r) * kH + k0 + scol, &Al[ch * 512]);
                }
                __syncthreads();
#pragma unroll
                for (int ks = 0; ks < 2; ++ks) {
                    int ks4 = (k0 >> 5) + ks;
                    bf16x8 ah = *(const bf16x8*)&Ah[(wv * 16 + lrow) * 64 + ks * 32 + lk];
                    bf16x8 al = *(const bf16x8*)&Al[(wv * 16 + lrow) * 64 + ks * 32 + lk];
#pragma unroll
                    for (int nf = 0; nf < 8; ++nf) {
                        bf16x8 bh = *(const bf16x8*)&Wh[((nf * 8 + ks4) * 64 + lane) * 8];
                        bf16x8 bl = *(const bf16x8*)&Wl[((nf * 8 + ks4) * 64 + lane) * 8];
                        acc[nf] = __builtin_amdgcn_mfma_f32_16x16x32_bf16(ah, bh, acc[nf], 0, 0, 0);
                        acc[nf] = __builtin_amdgcn_mfma_f32_16x16x32_bf16(al, bh, acc[nf], 0, 0, 0);
                        acc[nf] = __builtin_amdgcn_mfma_f32_16x16x32_bf16(ah, bl, acc[nf], 0, 0, 0);
                    }
                }
                __syncthreads();
            }
        }
        // gate-fused epilogue: c in registers, h hi/lo -> write buf (t+1)&1
        __bf16* Hhn = ((t + 1) & 1) ? hhi1 : hhi0;
        __bf16* Hln = ((t + 1) & 1) ? hlo1 : hlo0;
#pragma unroll
        for (int jt = 0; jt < 2; ++jt)
#pragma unroll
            for (int r = 0; r < 4; ++r) {
                int b = m0 + wv * 16 + rq + r, j = j0 + jt * 16 + col;
                float gi = acc[0 * 2 + jt][r], gf = acc[1 * 2 + jt][r];
                float gg = acc[2 * 2 + jt][r], go = acc[3 * 2 + jt][r];
                float i_ = 1.f / (1.f + expf(-gi));
                float f_ = 1.f / (1.f + expf(-gf));
                float g_ = tanhf(gg);
                float o_ = 1.f / (1.f + expf(-go));
                float cn = f_ * c_reg[jt][r] + i_ * g_;
                c_reg[jt][r] = cn;
                float h = o_ * tanhf(cn);
                __bf16 hi = (__bf16)h;
                Hhn[(size_t)b * kH + j] = hi;
                Hln[(size_t)b * kH + j] = (__bf16)(h - (float)hi);
            }
        // inter-block barrier among the 8 blocks sharing mb (skip after last step)
        if (t < kS - 1) {
            __threadfence();                           // wb this thread's stores
            __syncthreads();                           // all threads fenced
            if (tid == 0) {
                __hip_atomic_fetch_add(&bar[mb], 1, __ATOMIC_RELEASE,
                                       __HIP_MEMORY_SCOPE_AGENT);
                while (__hip_atomic_load(&bar[mb], __ATOMIC_ACQUIRE,
                                         __HIP_MEMORY_SCOPE_AGENT) < 8 * (t + 1))
                    __builtin_amdgcn_s_sleep(2);
            }
            __syncthreads();                           // release block; L1 inv'd by acquire
        }
    }
}

__global__ void bias_relu(const float* __restrict__ acc, const float* __restrict__ bias,
                          float* __restrict__ out, int M, int N) {
    int i = blockIdx.x * blockDim.x + threadIdx.x;
    if (i < M * N) {
        int n = i % N;
        out[i] = fmaxf(acc[i] + bias[n], 0.f);
    }
}

// ---------------------------------------------------------------------------
// MFMA tap-pair fused conv1(3->16) + conv2(16->16), 3x3, pad 1, no act between.
constexpr int ICH = 16;   // img_s channel stride (bf16)
constexpr int MCH = 16;   // mid_s channel stride (bf16)

__global__ __launch_bounds__(256) void conv_fused_mfma(
    const float* __restrict__ img,     // (B,3,64,64)
    const float* __restrict__ all_w,   // (B,2768)
    __bf16* __restrict__ out) {        // (B,16,64,64) bf16
    const int b = blockIdx.y;
    const int y0 = blockIdx.x * 8;
    __shared__ __align__(16) __bf16 w1a[5 * 16 * 32];         // [pair][o][k]
    __shared__ __align__(16) __bf16 w2a[5 * 16 * 32];         // [pair][o][k]
    __shared__ float bias_s[32];                              // conv1 | conv2 bias
    __shared__ __align__(16) __bf16 img_s[12 * 66 * ICH];     // rows gy=y0-2..y0+9
    __shared__ __align__(16) __bf16 mid_s[10 * 66 * MCH];     // rows gy=y0-1..y0+8

    const int tid = threadIdx.x, lane = tid & 63, wave = tid >> 6;
    const float* wb = all_w + (size_t)b * kTotalW;

    for (int i = tid; i < 12 * 66 * ICH / 8; i += 256)
        ((uint4*)img_s)[i] = make_uint4(0u, 0u, 0u, 0u);
    for (int i = tid; i < 10 * 66 * MCH / 8; i += 256)
        ((uint4*)mid_s)[i] = make_uint4(0u, 0u, 0u, 0u);
    for (int i = tid; i < 2560; i += 256) {      // w1a: k=half*16+c, t=2p+half
        int p = i >> 9, rem = i & 511, o = rem >> 5, k = rem & 31;
        int half = k >> 4, c = k & 15, t = 2 * p + half;
        w1a[i] = (__bf16)((c < 3 && t < 9) ? wb[o * 27 + c * 9 + t] : 0.f);
    }
    for (int i = tid; i < 2560; i += 256) {      // w2a
        int p = i >> 9, rem = i & 511, o = rem >> 5, k = rem & 31;
        int half = k >> 4, c = k & 15, t = 2 * p + half;
        w2a[i] = (__bf16)((t < 9) ? wb[448 + (o * 16 + c) * 9 + t] : 0.f);
    }
    if (tid < 16) bias_s[tid] = wb[432 + tid];
    else if (tid < 32) bias_s[tid] = wb[2752 + (tid - 16)];
    __syncthreads();

    for (int i = tid; i < 3 * 12 * 64; i += 256) {
        int c = i / 768, rem = i - c * 768, r = rem >> 6, x = rem & 63;
        int gy = y0 - 2 + r;
        if (gy >= 0 && gy < 64)
            img_s[(r * 66 + (x + 1)) * ICH + c] =
                (__bf16)img[(((size_t)b * 3 + c) << 12) + (gy << 6) + x];
    }
    __syncthreads();

    const int n = lane & 15, half = lane >> 5;
    const int c0 = ((lane >> 4) & 1) * 8, o0 = (lane >> 4) * 4;
    int dy_[5], dx_[5];
#pragma unroll
    for (int p = 0; p < 5; ++p) {
        int t = 2 * p + half;
        dy_[p] = (t < 9) ? t / 3 : 0;
        dx_[p] = (t < 9) ? t % 3 : 0;
    }
    bf16x8 a1[5], a2[5];
#pragma unroll
    for (int p = 0; p < 5; ++p) {
        a1[p] = *(const bf16x8*)&w1a[p * 512 + n * 32 + (lane >> 4) * 8];
        a2[p] = *(const bf16x8*)&w2a[p * 512 + n * 32 + (lane >> 4) * 8];
    }

#pragma unroll
    for (int ti = 0; ti < 10; ++ti) {
        int tile = wave * 10 + ti;
        int rr = tile >> 2, xt = (tile & 3) * 16;
        int gy = y0 - 1 + rr;                    // mid row's global y
        if (gy >= 0 && gy < 64) {                // else: stays zero (conv2's padding)
            floatx4 acc = {};
#pragma unroll
            for (int p = 0; p < 5; ++p) {
                bf16x8 bfr = *(const bf16x8*)
                    &img_s[((rr + dy_[p]) * 66 + (xt + n + dx_[p])) * ICH + c0];
                acc = __builtin_amdgcn_mfma_f32_16x16x32_bf16(a1[p], bfr, acc, 0, 0, 0);
            }
            union { short4 s4; __bf16 h[4]; } u;
#pragma unroll
            for (int q = 0; q < 4; ++q) u.h[q] = (__bf16)(acc[q] + bias_s[o0 + q]);
            *(short4*)&mid_s[(rr * 66 + (xt + n + 1)) * MCH + o0] = u.s4;
        }
    }
    __syncthreads();

#pragma unroll
    for (int ti = 0; ti < 8; ++ti) {
        int tile = wave * 8 + ti;
        int rr = tile >> 2, xt = (tile & 3) * 16;
        floatx4 acc = {};
#pragma unroll
        for (int p = 0; p < 5; ++p) {
            bf16x8 bfr = *(const bf16x8*)
                &mid_s[((rr + dy_[p]) * 66 + (xt + n + dx_[p])) * MCH + c0];
            acc = __builtin_amdgcn_mfma_f32_16x16x32_bf16(a2[p], bfr, acc, 0, 0, 0);
        }
        int gy = y0 + rr, gx = xt + n;
#pragma unroll
        for (int q = 0; q < 4; ++q)
            out[(((size_t)b * 16 + o0 + q) * 64 + gy) * 64 + gx] =
                (__bf16)(acc[q] + bias_s[16 + o0 + q]);
    }
}

// ---------------------------------------------------------------------------
// Fused lin2+lin3: out(256,2). grid B, block 64.
__global__ __launch_bounds__(64) void lin23(
    const float* __restrict__ l1out,
    const float* __restrict__ lw2, const float* __restrict__ lb2,
    const float* __restrict__ lw3, const float* __restrict__ lb3,
    float* __restrict__ out) {
    const int b = blockIdx.x, j = threadIdx.x;
    __shared__ float row[512];
    __shared__ float s[64];
    for (int i = j; i < 512; i += 64) row[i] = l1out[(size_t)b * 512 + i];
    __syncthreads();
    float acc = lb2[j];
    for (int k = 0; k < 512; ++k) acc += row[k] * lw2[(size_t)k * 64 + j];
    s[j] = fmaxf(acc, 0.f);
    __syncthreads();
    if (j < 2) {
        float o = lb3[j];
        for (int k = 0; k < 64; ++k) o += s[k] * lw3[(size_t)k * 2 + j];
        out[(size_t)b * 2 + j] = o;
    }
}

// ---------------------------------------------------------------------------
extern "C" void kernel_launch(void* const* d_in, const int* in_sizes, int n_in,
                              void* d_out, int out_size, void* d_ws, size_t ws_size,
                              hipStream_t stream) {
    const int* questions = (const int*)d_in[0];
    const float* images  = (const float*)d_in[1];
    const float* emb     = (const float*)d_in[2];
    const float* w_ih    = (const float*)d_in[3];
    const float* w_hh    = (const float*)d_in[4];
    const float* b_ih    = (const float*)d_in[5];
    const float* b_hh    = (const float*)d_in[6];
    const float* hw1     = (const float*)d_in[7];
    const float* hb1     = (const float*)d_in[8];
    const float* hw2     = (const float*)d_in[9];
    const float* hb2     = (const float*)d_in[10];
    const float* hw3     = (const float*)d_in[11];
    const float* hb3     = (const float*)d_in[12];
    const float* lw1     = (const float*)d_in[13];
    const float* lb1     = (const float*)d_in[14];
    const float* lw2     = (const float*)d_in[15];
    const float* lb2     = (const float*)d_in[16];
    const float* lw3     = (const float*)d_in[17];
    const float* lb3     = (const float*)d_in[18];
    float* out = (float*)d_out;

    char* ws = (char*)d_ws;
    size_t off = 0;
    auto alloc = [&](size_t nbytes) -> void* {
        void* p = (void*)(ws + off);
        off += (nbytes + 255) & ~(size_t)255;
        return p;
    };
    // big (64MB) timeline (single stream, strictly ordered):
    //   [0..20MB)  xih fp32            (dead after LSTM)
    //   [24..47MB) w3t bf16            (dead after hw3 MFMA GEMM)
    //   [0..32MB)  conv out bf16       (written by conv_fused_mfma, after both above dead)
    float*  big   = (float*)alloc(64ull << 20);
    __bf16* lw1t  = (__bf16*)alloc((size_t)512 * 65536 * 2);   // lw1^T bf16
    __bf16* w1t   = (__bf16*)alloc((size_t)1024 * 256 * 2);    // hw1^T bf16
    __bf16* w2t   = (__bf16*)alloc((size_t)4096 * 1024 * 2);   // hw2^T bf16
    __bf16* embb  = (__bf16*)alloc((size_t)10000 * kE * 2);    // emb bf16
    __bf16* w_ihb = (__bf16*)alloc((size_t)1024 * kE * 2);     // w_ih bf16 (already (N,K))
    __bf16* whib  = (__bf16*)alloc((size_t)1024 * kH * 2);     // w_hh bf16 hi
    __bf16* wlob  = (__bf16*)alloc((size_t)1024 * kH * 2);     // w_hh bf16 lo residual
    __bf16* hhi0  = (__bf16*)alloc((size_t)kB * kH * 2);       // h hi ping-pong
    __bf16* hlo0  = (__bf16*)alloc((size_t)kB * kH * 2);
    __bf16* hhi1  = (__bf16*)alloc((size_t)kB * kH * 2);
    __bf16* hlo1  = (__bf16*)alloc((size_t)kB * kH * 2);
    __bf16* h1b   = (__bf16*)alloc((size_t)kB * 1024 * 2);
    __bf16* h2b   = (__bf16*)alloc((size_t)kB * 4096 * 2);
    // contiguous fp32 accumulators (zeroed in one kernel): hw1 | hw2 | hw3 | lin1 | bar
    const int nACC = kB * (1024 + 4096 + 2768 + 512);
    float*  accz  = (float*)alloc((size_t)(nACC + 64) * sizeof(float));
    float*  accA  = accz;
    float*  accB  = accA + (size_t)kB * 1024;
    float*  accC  = accB + (size_t)kB * 4096;
    float*  acc1  = accC + (size_t)kB * 2768;
    int*    bar   = (int*)(accz + nACC);                       // int[4] barrier counters
    float*  allw  = (float*)alloc((size_t)kB * kTotalW * sizeof(float));
    float*  l1out = (float*)alloc((size_t)kB * 512 * sizeof(float));

    float*  xih    = big;
    __bf16* c2out  = (__bf16*)big;
    __bf16* w3t    = (__bf16*)((char*)big + (24ull << 20));    // 2768 x 4096 bf16
    zero_f32<<<512, 256, 0, stream>>>(accz, nACC + 64);

    // weight converts/transposes (regions disjoint from their concurrent readers/writers)
    cvt_bf16<<<1280, 256, 0, stream>>>(emb, embb, 10000 * kE);
    cvt_bf16<<<128, 256, 0, stream>>>(w_ih, w_ihb, 1024 * kE);
    wsplit_bf16<<<256, 256, 0, stream>>>(w_hh, whib, wlob, 1024 * kH);
    transpose_cvt<<<dim3(8, 32),   256, 0, stream>>>(hw1, w1t, 256, 1024);
    transpose_cvt<<<dim3(32, 128), 256, 0, stream>>>(hw2, w2t, 1024, 4096);
    transpose_cvt<<<dim3(128, 87), 256, 0, stream>>>(hw3, w3t, 4096, 2768);
    transpose_cvt<<<dim3(2048, 16), 256, 0, stream>>>(lw1, lw1t, 65536, 512);

    // 1) xih = emb[q] @ w_ih^T + b_ih + b_hh via MFMA, laid out (S,B,4H)
    xih_mfma<<<dim3(80, 16), 256, 0, stream>>>(questions, embb, w_ihb, b_ih, b_hh, xih);

    // 2) all 20 LSTM steps in ONE persistent kernel (W in LDS, spin barriers)
    lstm_persist<<<dim3(4, 8), 256, 0, stream>>>(
        xih, whib, wlob, hhi0, hlo0, hhi1, hlo1, bar);
    __bf16* h0b = hhi0;   // step 19 writes buffer (19+1)&1 = 0

    // 3) hyper-MLP via bf16 MFMA split-K GEMMs (128x128 tile, global_load_lds)
    mfma128<<<dim3(2, 8, 4),  256, 0, stream>>>(h0b, w1t, accA, 256, 1024, 256, 64);
    ep_lrelu_bf16<<<1024, 256, 0, stream>>>(accA, hb1, h1b, 256, 1024);
    mfma128<<<dim3(2, 32, 4), 256, 0, stream>>>(h1b, w2t, accB, 256, 4096, 1024, 256);
    ep_lrelu_bf16<<<4096, 256, 0, stream>>>(accB, hb2, h2b, 256, 4096);
    mfma128<<<dim3(2, 22, 8), 256, 0, stream>>>(h2b, w3t, accC, 256, 2768, 4096, 512);
    ep_bias_f32<<<2768, 256, 0, stream>>>(accC, hb3, allw, 256, 2768);

    // 4) fused conv1+conv2 via MFMA tap-pair implicit GEMM -> bf16
    conv_fused_mfma<<<dim3(8, 256), 256, 0, stream>>>(images, allw, c2out);

    // 5) lin1 via bf16 MFMA split-K: 256x512, K=65536, splits=64 (512 blocks, 16 iters)
    mfma128<<<dim3(2, 4, 64), 256, 0, stream>>>(c2out, lw1t, acc1, 256, 512, 65536, 1024);
    bias_relu<<<512, 256, 0, stream>>>(acc1, lb1, l1out, 256, 512);

    // 6) lin2+lin3 fused -> out (256,2)
    lin23<<<256, 64, 0, stream>>>(l1out, lw2, lb2, lw3, lb3, out);
}